// Round 19
// baseline (174.328 us; speedup 1.0000x reference)
//
#include <hip/hip_runtime.h>
#include <hip/hip_bf16.h>
#include <math.h>

// Problem shape (fixed): B=8, L=2048, D=1024, n=16, d=64
#define BATCH 8
#define SEQL  2048
#define DIM   1024
#define MROWS (BATCH * SEQL)   // 16384

typedef _Float16 f16;
typedef _Float16 f16x8 __attribute__((ext_vector_type(8)));
typedef _Float16 f16x4 __attribute__((ext_vector_type(4)));
typedef _Float16 f16x2 __attribute__((ext_vector_type(2)));
typedef float f32x4 __attribute__((ext_vector_type(4)));

typedef const __attribute__((address_space(1))) void* gp_t;
typedef __attribute__((address_space(3))) void* lp_t;
#define GLL(src, dst) __builtin_amdgcn_global_load_lds((gp_t)(src), (lp_t)(dst), 16, 0, 0)

// ---------------------------------------------------------------------------
// merged fp32->f16 converts: x -> xh, Wk|Wkg -> Wcat, Wout -> Wouth. One dispatch.
__global__ __launch_bounds__(256) void cvt_all(const float* __restrict__ x,
                                               const float* __restrict__ Wk,
                                               const float* __restrict__ Wkg,
                                               const float* __restrict__ Wout,
                                               f16* __restrict__ xh,
                                               f16* __restrict__ Wcat,
                                               f16* __restrict__ Wouth)
{
    int i = blockIdx.x * 256 + threadIdx.x;          // 8-elem groups
    const float* src; f16* dst;
    if (i < 2097152)      { src = x;    dst = xh;             }
    else if (i < 2228224) { src = Wk;   dst = Wcat;           i -= 2097152; }
    else if (i < 2359296) { src = Wkg;  dst = Wcat + 1048576; i -= 2228224; }
    else                  { src = Wout; dst = Wouth;          i -= 2359296; }
    const float4* p = (const float4*)src + (size_t)i * 2;
    const float4 a = p[0], b = p[1];
    f16x8 v;
    v[0] = (f16)a.x; v[1] = (f16)a.y; v[2] = (f16)a.z; v[3] = (f16)a.w;
    v[4] = (f16)b.x; v[5] = (f16)b.y; v[6] = (f16)b.z; v[7] = (f16)b.w;
    *(f16x8*)(dst + (size_t)i * 8) = v;
}

// ---------------------------------------------------------------------------
// 256x256-tile 8-phase f16 MFMA GEMM, 64 KB LDS, swapped-operand MFMA with
// packed epilogue (R18-proven, 90.5us kg) + A-FRAGMENT READ-AHEAD:
// phase p+1's A ds_reads are issued at the END of phase p (after its MFMAs),
// overlapping the vmcnt-wait + barrier; the next lgkmcnt(0) finds them
// drained. Two alternating reg sets aA/aB (static indexing).
// Rotation guarantees quarter q+1(t) is staged >=2 phases before its read;
// guards re-derived from the per-wave issue queue (stage sequence identical
// across waves, so per-wave vmcnt + barrier = cross-wave visibility):
// steady {P0:1, P1:1, P2:3, P3:3}; last tile {1,1,0,0}. Never vmcnt(0)
// mid-loop except the peeled tail.
// MODE 0: fp32 C0, N=1024.  MODE 1: N=2048 split: col<1024 -> f16 k (C0),
// col>=1024 -> sigmoid(+bias) f16 g (C1).
template<int MODE>
__global__ __launch_bounds__(512, 2) void gemm8(const f16* __restrict__ A,
                                                const f16* __restrict__ Bw,
                                                const float* __restrict__ bias,
                                                void* __restrict__ C0,
                                                void* __restrict__ C1)
{
    constexpr int K   = 1024;
    constexpr int NTI = MODE ? 8 : 4;   // N/256
    constexpr int NKT = 16;             // K/64
    __shared__ f16 ldsA[256 * 64];      // 32 KiB, quarter-rotated
    __shared__ f16 ldsB[256 * 64];      // 32 KiB, whole-rotated after p0

    const int tid = threadIdx.x;
    const int w = tid >> 6, l = tid & 63;
    const int wm = w >> 2, wn = w & 3;
    const int lrow = l & 15;
    const int l7 = l & 7, lk = l >> 4;

    // bijective XCD swizzle (grid % 8 == 0)
    const int cpx = gridDim.x >> 3;
    const int lt  = (blockIdx.x & 7) * cpx + (blockIdx.x >> 3);
    const int bm  = (lt / NTI) * 256;
    const int bn  = (lt % NTI) * 256;

    // staging geometry
    const int srl   = tid >> 3;                 // 0..63
    const int sg    = tid & 7;                  // LDS granule slot
    const int scolx = (sg ^ (srl & 7)) * 8;     // inverse-swizzled source col
    const int aR0 = (srl < 32) ? srl : (96 + srl);

    // swizzled ds-read granule offsets (elems) for ks=0/1
    const int g0 = ((lk) ^ l7) * 8;
    const int g1 = ((4 + lk) ^ l7) * 8;

#define STAGE_AQ(tt, p)                                                                  \
    do {                                                                                 \
        const int _R = 32 * (p) + aR0;                                                   \
        GLL(A + (size_t)(bm + _R) * K + (tt) * 64 + scolx, ldsA + _R * 64 + sg * 8);     \
    } while (0)

#define STAGE_BH(tt, h)                                                                  \
    do {                                                                                 \
        const int _r0 = (h) * 128 + srl;                                                 \
        GLL(Bw + (size_t)(bn + _r0) * K + (tt) * 64 + scolx, ldsB + _r0 * 64 + sg * 8);  \
        const int _r1 = _r0 + 64;                                                        \
        GLL(Bw + (size_t)(bn + _r1) * K + (tt) * 64 + scolx, ldsB + _r1 * 64 + sg * 8);  \
    } while (0)

#define READ_A(q, dst)                                                                   \
    do {                                                                                 \
        const int _ar = (wm * 128 + 32 * (q) + lrow) * 64;                               \
        dst[0] = *(const f16x8*)(ldsA + _ar + g0);                                       \
        dst[1] = *(const f16x8*)(ldsA + _ar + g1);                                       \
        dst[2] = *(const f16x8*)(ldsA + _ar + 1024 + g0);                                \
        dst[3] = *(const f16x8*)(ldsA + _ar + 1024 + g1);                                \
    } while (0)

    f32x4 acc[8][4];
    #pragma unroll
    for (int mi = 0; mi < 8; ++mi)
        #pragma unroll
        for (int ni = 0; ni < 4; ++ni) acc[mi][ni] = (f32x4){0.f, 0.f, 0.f, 0.f};

    f16x8 bf[4][2];
    f16x8 aA[4], aB[4];   // alternating A-fragment sets

    // PHASE: AREG = regs holding THIS phase's quarter (pre-read);
    // RA_Q/RA_DST: quarter to read-ahead at phase end (RA_Q<0 = none).
#define PHASE(p, VK, STG, AREG, RA_Q, RA_DST)                                            \
    do {                                                                                 \
        asm volatile("s_waitcnt vmcnt(" #VK ")" ::: "memory");                           \
        __builtin_amdgcn_s_barrier();                                                    \
        if ((p) == 0) {                                                                  \
            _Pragma("unroll")                                                            \
            for (int ni = 0; ni < 4; ++ni) {                                             \
                const int _br = (wn * 64 + ni * 16 + lrow) * 64;                         \
                bf[ni][0] = *(const f16x8*)(ldsB + _br + g0);                            \
                bf[ni][1] = *(const f16x8*)(ldsB + _br + g1);                            \
            }                                                                            \
        }                                                                                \
        STG;                                                                             \
        asm volatile("s_waitcnt lgkmcnt(0)" ::: "memory");                               \
        __builtin_amdgcn_sched_barrier(0);                                               \
        __builtin_amdgcn_s_setprio(1);                                                   \
        _Pragma("unroll")                                                                \
        for (int ni = 0; ni < 4; ++ni) {                                                 \
            acc[2*(p)][ni]   = __builtin_amdgcn_mfma_f32_16x16x32_f16(bf[ni][0], AREG[0], acc[2*(p)][ni], 0, 0, 0);   \
            acc[2*(p)][ni]   = __builtin_amdgcn_mfma_f32_16x16x32_f16(bf[ni][1], AREG[1], acc[2*(p)][ni], 0, 0, 0);   \
            acc[2*(p)+1][ni] = __builtin_amdgcn_mfma_f32_16x16x32_f16(bf[ni][0], AREG[2], acc[2*(p)+1][ni], 0, 0, 0); \
            acc[2*(p)+1][ni] = __builtin_amdgcn_mfma_f32_16x16x32_f16(bf[ni][1], AREG[3], acc[2*(p)+1][ni], 0, 0, 0); \
        }                                                                                \
        __builtin_amdgcn_s_setprio(0);                                                   \
        if ((RA_Q) >= 0) READ_A(RA_Q, RA_DST);                                           \
    } while (0)

    // prologue: stage [Bh0(0)x2, Aq0(0), Bh1(0)x2, Aq1(0), Aq2(0)] = 7 loads.
    // vmcnt(4) forces Bh0+Aq0 across all waves (symmetric queues) -> after
    // the barrier, quarter 0 is fully visible; pre-read it into aA.
    STAGE_BH(0, 0); STAGE_AQ(0, 0);
    STAGE_BH(0, 1); STAGE_AQ(0, 1);
    STAGE_AQ(0, 2);
    asm volatile("s_waitcnt vmcnt(4)" ::: "memory");
    __builtin_amdgcn_s_barrier();
    READ_A(0, aA);

    for (int t = 0; t < NKT - 1; ++t) {
        PHASE(0, 1, { STAGE_AQ(t, 3); },                          aA, 1, aB);
        PHASE(1, 1, { STAGE_BH(t + 1, 0); STAGE_AQ(t + 1, 0); },  aB, 2, aA);
        PHASE(2, 3, { STAGE_BH(t + 1, 1); STAGE_AQ(t + 1, 1); },  aA, 3, aB);
        PHASE(3, 3, { STAGE_AQ(t + 1, 2); },                      aB, 0, aA);
    }
    // last tile: no next-tile stages; peeled guards {1,1,0,0}
    PHASE(0, 1, { STAGE_AQ(NKT - 1, 3); }, aA, 1, aB);
    PHASE(1, 1, {},                        aB, 2, aA);
    PHASE(2, 0, {},                        aA, 3, aB);
    PHASE(3, 0, {},                        aB, -1, aA);
#undef PHASE
#undef READ_A
#undef STAGE_AQ
#undef STAGE_BH

    // epilogue (swapped-operand layout): lane l holds C[m][n0..n0+3],
    // m = ... + (l&15), n0 = ... + (l>>4)*4  -> one packed store per fragment.
    const int mrow  = l & 15;
    const int ncol0 = (l >> 4) * 4;
    #pragma unroll
    for (int mi = 0; mi < 8; ++mi) {
        const int m = bm + wm * 128 + mi * 16 + mrow;
        #pragma unroll
        for (int ni = 0; ni < 4; ++ni) {
            const int n0 = bn + wn * 64 + ni * 16 + ncol0;
            const f32x4 v = acc[mi][ni];
            if (MODE == 0) {
                *(f32x4*)((float*)C0 + (size_t)m * DIM + n0) = v;
            } else {
                if (n0 < DIM) {
                    f16x4 o;
                    o[0] = (f16)v[0]; o[1] = (f16)v[1]; o[2] = (f16)v[2]; o[3] = (f16)v[3];
                    *(f16x4*)((f16*)C0 + (size_t)m * DIM + n0) = o;          // k
                } else {
                    const f32x4 bv = *(const f32x4*)(bias + (n0 - DIM));
                    f16x4 o;
                    #pragma unroll
                    for (int r = 0; r < 4; ++r)
                        o[r] = (f16)(1.f / (1.f + __expf(-(v[r] + bv[r]))));  // g
                    *(f16x4*)((f16*)C1 + (size_t)m * DIM + (n0 - DIM)) = o;
                }
            }
        }
    }
}

// ---------------------------------------------------------------------------
// DPP cross-lane add (VALU latency). CTRL compile-time.
template<int CTRL>
__device__ __forceinline__ float dpp_add_f(float s) {
    int t = __builtin_amdgcn_update_dpp(0, __float_as_int(s), CTRL, 0xF, 0xF, true);
    return s + __int_as_float(t);
}

__device__ __forceinline__ float sumsq4(f16x2 a, f16x2 b) {
    return __builtin_amdgcn_fdot2(a, a, __builtin_amdgcn_fdot2(b, b, 0.f, false), false);
}

#define PF 16     // prefetch depth (steps)
#define CHK 64    // output chunk length
#define WARM 96   // speculative warmup (contraction ~0.58/step -> err ~e^-35 << f16 ulp)

// Speculative chunked scan (R15/R18-proven): 1024 blocks = 32 wave-groups x
// 32 chunks; chunk c re-scans from h=0 at t=max(0,c*64-96), discards warmup
// (exact for c<=1), writes [c*64,(c+1)*64). Wall: 160 steps.
__global__ __launch_bounds__(64) void scan_kernel(const f16* __restrict__ Kv,
                                                  const f16* __restrict__ Gv,
                                                  f16* __restrict__ Ov)
{
    const int w = blockIdx.x & 31;    // wave-group: batch w>>2, quad w&3
    const int c = blockIdx.x >> 5;    // chunk 0..31
    const int l = threadIdx.x;

    const int tc   = c * CHK;
    const int t0   = (tc > WARM) ? (tc - WARM) : 0;
    const int warm = tc - t0;         // 0, 64, or 96 (all multiples of PF)

    const size_t base = (size_t)(w >> 2) * (SEQL * DIM) + (size_t)((w & 3) * 256 + l * 4);
    size_t off = base + (size_t)t0 * DIM;

    f16x2 h01 = (f16x2){(f16)0.f, (f16)0.f};
    f16x2 h23 = (f16x2){(f16)0.f, (f16)0.f};

    f16x4 kb[PF], gb[PF];
    #pragma unroll
    for (int u = 0; u < PF; ++u) {
        kb[u] = *(const f16x4*)(Kv + off + (size_t)u * DIM);
        gb[u] = *(const f16x4*)(Gv + off + (size_t)u * DIM);
    }

    #define SCAN_STEP(kc, gc, DO_ST)                                                   \
        do {                                                                           \
            const f16x2 k01 = __builtin_shufflevector((kc), (kc), 0, 1);               \
            const f16x2 k23 = __builtin_shufflevector((kc), (kc), 2, 3);               \
            const f16x2 g01 = __builtin_shufflevector((gc), (gc), 0, 1);               \
            const f16x2 g23 = __builtin_shufflevector((gc), (gc), 2, 3);               \
            const f16x2 u01 = h01 * g01;                                               \
            const f16x2 u23 = h23 * g23;                                               \
            float s = sumsq4(h01, h23);                                                \
            s = dpp_add_f<0xB1>(s);                                                    \
            s = dpp_add_f<0x4E>(s);                                                    \
            s = dpp_add_f<0x141>(s);                                                   \
            s = dpp_add_f<0x140>(s);                                                   \
            const float inv = __builtin_amdgcn_rsqf(fmaf(s, 0.015625f, 1e-8f));        \
            const f16 ih = (f16)inv;                                                   \
            const f16x2 iv = (f16x2){ih, ih};                                          \
            h01 = u01 * iv + k01;                                                      \
            h23 = u23 * iv + k23;                                                      \
            if (DO_ST) {                                                               \
                f16x4 o;                                                               \
                o[0] = h01[0]; o[1] = h01[1]; o[2] = h23[0]; o[3] = h23[1];            \
                *(f16x4*)(Ov + off) = o;                                               \
            }                                                                          \
            off += DIM;                                                                \
        } while (0)

    for (int tb = 0; tb < warm; tb += PF) {
        #pragma unroll
        for (int u = 0; u < PF; ++u) {
            const f16x4 kc = kb[u], gc = gb[u];
            const size_t poff = off + (size_t)PF * DIM;
            kb[u] = *(const f16x4*)(Kv + poff);
            gb[u] = *(const f16x4*)(Gv + poff);
            SCAN_STEP(kc, gc, 0);
        }
    }
    for (int tb = 0; tb < CHK - PF; tb += PF) {
        #pragma unroll
        for (int u = 0; u < PF; ++u) {
            const f16x4 kc = kb[u], gc = gb[u];
            const size_t poff = off + (size_t)PF * DIM;
            kb[u] = *(const f16x4*)(Kv + poff);
            gb[u] = *(const f16x4*)(Gv + poff);
            SCAN_STEP(kc, gc, 1);
        }
    }
    #pragma unroll
    for (int u = 0; u < PF; ++u) {
        const f16x4 kc = kb[u], gc = gb[u];
        SCAN_STEP(kc, gc, 1);
    }
    #undef SCAN_STEP
}

// ---------------------------------------------------------------------------
extern "C" void kernel_launch(void* const* d_in, const int* in_sizes, int n_in,
                              void* d_out, int out_size, void* d_ws, size_t ws_size,
                              hipStream_t stream) {
    const float* x    = (const float*)d_in[0];
    const float* Wk   = (const float*)d_in[1];
    const float* Wkg  = (const float*)d_in[2];
    const float* bkg  = (const float*)d_in[3];
    const float* Wout = (const float*)d_in[4];
    float* out = (float*)d_out;

    // workspace (f16): xh/Kh/Gh 32MB each + Wcat 4MB + Wouth 2MB = 102MB
    f16* xh    = (f16*)d_ws;                         // [M, D]; scan output reuses it
    f16* Kh    = xh    + (size_t)MROWS * DIM;
    f16* Gh    = Kh    + (size_t)MROWS * DIM;
    f16* Wcat  = Gh    + (size_t)MROWS * DIM;        // [2048, 1024]: Wk ; Wkg
    f16* Wouth = Wcat  + (size_t)2 * DIM * DIM;

    // merged converts: one dispatch (x + Wk + Wkg + Wout), 9728 blocks
    cvt_all<<<dim3(9728), dim3(256), 0, stream>>>(x, Wk, Wkg, Wout, xh, Wcat, Wouth);

    // fused k|g GEMM: M=16384, N=2048 -> 64 x 8 = 512 blocks (2/CU resident)
    gemm8<1><<<dim3(512), dim3(512), 0, stream>>>(xh, Wcat, bkg, Kh, Gh);
    // speculative chunked scan: 32 wave-groups x 32 chunks = 1024 blocks
    scan_kernel<<<dim3(1024), dim3(64), 0, stream>>>(Kh, Gh, xh);
    // out = o @ Wout.T: 64 x 4 = 256 blocks
    gemm8<0><<<dim3(256), dim3(512), 0, stream>>>(xh, Wouth, nullptr, out, nullptr);
}

// Round 20
// 161.602 us; speedup vs baseline: 1.0787x; 1.0787x over previous
//
#include <hip/hip_runtime.h>
#include <hip/hip_bf16.h>
#include <math.h>

// Problem shape (fixed): B=8, L=2048, D=1024, n=16, d=64
#define BATCH 8
#define SEQL  2048
#define DIM   1024
#define MROWS (BATCH * SEQL)   // 16384

typedef _Float16 f16;
typedef _Float16 f16x8 __attribute__((ext_vector_type(8)));
typedef _Float16 f16x4 __attribute__((ext_vector_type(4)));
typedef _Float16 f16x2 __attribute__((ext_vector_type(2)));
typedef float f32x4 __attribute__((ext_vector_type(4)));

typedef const __attribute__((address_space(1))) void* gp_t;
typedef __attribute__((address_space(3))) void* lp_t;
#define GLL(src, dst) __builtin_amdgcn_global_load_lds((gp_t)(src), (lp_t)(dst), 16, 0, 0)

// ---------------------------------------------------------------------------
// merged fp32->f16 converts: x -> xh, Wk|Wkg -> Wcat, Wout -> Wouth. One dispatch.
__global__ __launch_bounds__(256) void cvt_all(const float* __restrict__ x,
                                               const float* __restrict__ Wk,
                                               const float* __restrict__ Wkg,
                                               const float* __restrict__ Wout,
                                               f16* __restrict__ xh,
                                               f16* __restrict__ Wcat,
                                               f16* __restrict__ Wouth)
{
    int i = blockIdx.x * 256 + threadIdx.x;          // 8-elem groups
    const float* src; f16* dst;
    if (i < 2097152)      { src = x;    dst = xh;             }
    else if (i < 2228224) { src = Wk;   dst = Wcat;           i -= 2097152; }
    else if (i < 2359296) { src = Wkg;  dst = Wcat + 1048576; i -= 2228224; }
    else                  { src = Wout; dst = Wouth;          i -= 2359296; }
    const float4* p = (const float4*)src + (size_t)i * 2;
    const float4 a = p[0], b = p[1];
    f16x8 v;
    v[0] = (f16)a.x; v[1] = (f16)a.y; v[2] = (f16)a.z; v[3] = (f16)a.w;
    v[4] = (f16)b.x; v[5] = (f16)b.y; v[6] = (f16)b.z; v[7] = (f16)b.w;
    *(f16x8*)(dst + (size_t)i * 8) = v;
}

// ---------------------------------------------------------------------------
// 256x256-tile 8-phase f16 MFMA GEMM, 64 KB LDS (R18-proven best: kg 90.5us),
// swapped-operand MFMA (mfma(bf, af) -> D = C^T fragments: lane l holds
// C[m=base+(l&15)][n=nbase+(l>>4)*4+r] -> one packed store per fragment).
//  - A: single 32KB image, quarter-rotated (phase p reads A-quarter p; q of
//    t+1 staged at phase q+1). B: single 32KB image, consumed into regs at
//    p0; B(t+1) staged at p1/p2. Counted vmcnt {2,2,4,6}, last tile {2,2,1,0}.
// MODE 0: fp32 C0, N=1024.  MODE 1: N=2048 split: col<1024 -> f16 k (C0),
// col>=1024 -> sigmoid(+bias) f16 g (C1).
template<int MODE>
__global__ __launch_bounds__(512, 2) void gemm8(const f16* __restrict__ A,
                                                const f16* __restrict__ Bw,
                                                const float* __restrict__ bias,
                                                void* __restrict__ C0,
                                                void* __restrict__ C1)
{
    constexpr int K   = 1024;
    constexpr int NTI = MODE ? 8 : 4;   // N/256
    constexpr int NKT = 16;             // K/64
    __shared__ f16 ldsA[256 * 64];      // 32 KiB, quarter-rotated
    __shared__ f16 ldsB[256 * 64];      // 32 KiB, whole-rotated after p0

    const int tid = threadIdx.x;
    const int w = tid >> 6, l = tid & 63;
    const int wm = w >> 2, wn = w & 3;
    const int lrow = l & 15;
    const int l7 = l & 7, lk = l >> 4;

    // bijective XCD swizzle (grid % 8 == 0)
    const int cpx = gridDim.x >> 3;
    const int lt  = (blockIdx.x & 7) * cpx + (blockIdx.x >> 3);
    const int bm  = (lt / NTI) * 256;
    const int bn  = (lt % NTI) * 256;

    // staging geometry
    const int srl   = tid >> 3;                 // 0..63
    const int sg    = tid & 7;                  // LDS granule slot
    const int scolx = (sg ^ (srl & 7)) * 8;     // inverse-swizzled source col
    const int aR0 = (srl < 32) ? srl : (96 + srl);

    // swizzled ds-read granule offsets (elems) for ks=0/1
    const int g0 = ((lk) ^ l7) * 8;
    const int g1 = ((4 + lk) ^ l7) * 8;

#define STAGE_AQ(tt, p)                                                                  \
    do {                                                                                 \
        const int _R = 32 * (p) + aR0;                                                   \
        GLL(A + (size_t)(bm + _R) * K + (tt) * 64 + scolx, ldsA + _R * 64 + sg * 8);     \
    } while (0)

#define STAGE_BH(tt, h)                                                                  \
    do {                                                                                 \
        const int _r0 = (h) * 128 + srl;                                                 \
        GLL(Bw + (size_t)(bn + _r0) * K + (tt) * 64 + scolx, ldsB + _r0 * 64 + sg * 8);  \
        const int _r1 = _r0 + 64;                                                        \
        GLL(Bw + (size_t)(bn + _r1) * K + (tt) * 64 + scolx, ldsB + _r1 * 64 + sg * 8);  \
    } while (0)

    f32x4 acc[8][4];
    #pragma unroll
    for (int mi = 0; mi < 8; ++mi)
        #pragma unroll
        for (int ni = 0; ni < 4; ++ni) acc[mi][ni] = (f32x4){0.f, 0.f, 0.f, 0.f};

    f16x8 bf[4][2];

#define PHASE(p, VK, STG)                                                                \
    do {                                                                                 \
        asm volatile("s_waitcnt vmcnt(" #VK ")" ::: "memory");                           \
        __builtin_amdgcn_s_barrier();                                                    \
        const int _ar = (wm * 128 + 32 * (p) + lrow) * 64;                               \
        f16x8 a00 = *(const f16x8*)(ldsA + _ar + g0);                                    \
        f16x8 a01 = *(const f16x8*)(ldsA + _ar + g1);                                    \
        f16x8 a10 = *(const f16x8*)(ldsA + _ar + 1024 + g0);                             \
        f16x8 a11 = *(const f16x8*)(ldsA + _ar + 1024 + g1);                             \
        if ((p) == 0) {                                                                  \
            _Pragma("unroll")                                                            \
            for (int ni = 0; ni < 4; ++ni) {                                             \
                const int _br = (wn * 64 + ni * 16 + lrow) * 64;                         \
                bf[ni][0] = *(const f16x8*)(ldsB + _br + g0);                            \
                bf[ni][1] = *(const f16x8*)(ldsB + _br + g1);                            \
            }                                                                            \
        }                                                                                \
        STG;                                                                             \
        asm volatile("s_waitcnt lgkmcnt(0)" ::: "memory");                               \
        __builtin_amdgcn_sched_barrier(0);                                               \
        __builtin_amdgcn_s_setprio(1);                                                   \
        _Pragma("unroll")                                                                \
        for (int ni = 0; ni < 4; ++ni) {                                                 \
            acc[2*(p)][ni]   = __builtin_amdgcn_mfma_f32_16x16x32_f16(bf[ni][0], a00, acc[2*(p)][ni], 0, 0, 0);   \
            acc[2*(p)][ni]   = __builtin_amdgcn_mfma_f32_16x16x32_f16(bf[ni][1], a01, acc[2*(p)][ni], 0, 0, 0);   \
            acc[2*(p)+1][ni] = __builtin_amdgcn_mfma_f32_16x16x32_f16(bf[ni][0], a10, acc[2*(p)+1][ni], 0, 0, 0); \
            acc[2*(p)+1][ni] = __builtin_amdgcn_mfma_f32_16x16x32_f16(bf[ni][1], a11, acc[2*(p)+1][ni], 0, 0, 0); \
        }                                                                                \
        __builtin_amdgcn_s_setprio(0);                                                   \
    } while (0)

    // prologue, steady-state issue order: [Bh0 x2, Aq0, Bh1 x2, Aq1, Aq2] of t=0
    STAGE_BH(0, 0); STAGE_AQ(0, 0);
    STAGE_BH(0, 1); STAGE_AQ(0, 1);
    STAGE_AQ(0, 2);

    for (int t = 0; t < NKT - 1; ++t) {
        PHASE(0, 2, { STAGE_AQ(t, 3); });
        PHASE(1, 2, { STAGE_BH(t + 1, 0); STAGE_AQ(t + 1, 0); });
        PHASE(2, 4, { STAGE_BH(t + 1, 1); STAGE_AQ(t + 1, 1); });
        PHASE(3, 6, { STAGE_AQ(t + 1, 2); });
    }
    // last tile: no next-tile stages; shallow queue -> tighter guards
    PHASE(0, 2, { STAGE_AQ(NKT - 1, 3); });
    PHASE(1, 2, {});
    PHASE(2, 1, {});
    PHASE(3, 0, {});
#undef PHASE
#undef STAGE_AQ
#undef STAGE_BH

    // epilogue (swapped-operand layout): lane l holds C[m][n0..n0+3],
    // m = ... + (l&15), n0 = ... + (l>>4)*4  -> one packed store per fragment.
    const int mrow  = l & 15;
    const int ncol0 = (l >> 4) * 4;
    #pragma unroll
    for (int mi = 0; mi < 8; ++mi) {
        const int m = bm + wm * 128 + mi * 16 + mrow;
        #pragma unroll
        for (int ni = 0; ni < 4; ++ni) {
            const int n0 = bn + wn * 64 + ni * 16 + ncol0;
            const f32x4 v = acc[mi][ni];
            if (MODE == 0) {
                *(f32x4*)((float*)C0 + (size_t)m * DIM + n0) = v;
            } else {
                if (n0 < DIM) {
                    f16x4 o;
                    o[0] = (f16)v[0]; o[1] = (f16)v[1]; o[2] = (f16)v[2]; o[3] = (f16)v[3];
                    *(f16x4*)((f16*)C0 + (size_t)m * DIM + n0) = o;          // k
                } else {
                    const f32x4 bv = *(const f32x4*)(bias + (n0 - DIM));
                    f16x4 o;
                    #pragma unroll
                    for (int r = 0; r < 4; ++r)
                        o[r] = (f16)(1.f / (1.f + __expf(-(v[r] + bv[r]))));  // g
                    *(f16x4*)((f16*)C1 + (size_t)m * DIM + (n0 - DIM)) = o;
                }
            }
        }
    }
}

// ---------------------------------------------------------------------------
// DPP cross-lane add (VALU latency). CTRL compile-time.
template<int CTRL>
__device__ __forceinline__ float dpp_add_f(float s) {
    int t = __builtin_amdgcn_update_dpp(0, __float_as_int(s), CTRL, 0xF, 0xF, true);
    return s + __int_as_float(t);
}

__device__ __forceinline__ float sumsq4(f16x2 a, f16x2 b) {
    return __builtin_amdgcn_fdot2(a, a, __builtin_amdgcn_fdot2(b, b, 0.f, false), false);
}

#define PF 16     // prefetch depth (steps)
#define CHK 64    // output chunk length
#define WARM 64   // speculative warmup (contraction ~0.58/step -> err ~2e-9 << f16 ulp;
                  // mechanism validated at WARM=128 (R15) and 96 (R18), absmax identical)

// Speculative chunked scan: 1024 blocks = 32 wave-groups x 32 chunks; chunk c
// re-scans from h=0 at t=max(0,c*64-64), discards warmup (exact for c<=1),
// writes [c*64,(c+1)*64). Wall: 128 steps instead of 2048.
__global__ __launch_bounds__(64) void scan_kernel(const f16* __restrict__ Kv,
                                                  const f16* __restrict__ Gv,
                                                  f16* __restrict__ Ov)
{
    const int w = blockIdx.x & 31;    // wave-group: batch w>>2, quad w&3
    const int c = blockIdx.x >> 5;    // chunk 0..31
    const int l = threadIdx.x;

    const int tc   = c * CHK;
    const int t0   = (tc > WARM) ? (tc - WARM) : 0;
    const int warm = tc - t0;         // 0 or 64 (multiples of PF)

    const size_t base = (size_t)(w >> 2) * (SEQL * DIM) + (size_t)((w & 3) * 256 + l * 4);
    size_t off = base + (size_t)t0 * DIM;

    f16x2 h01 = (f16x2){(f16)0.f, (f16)0.f};
    f16x2 h23 = (f16x2){(f16)0.f, (f16)0.f};

    f16x4 kb[PF], gb[PF];
    #pragma unroll
    for (int u = 0; u < PF; ++u) {
        kb[u] = *(const f16x4*)(Kv + off + (size_t)u * DIM);
        gb[u] = *(const f16x4*)(Gv + off + (size_t)u * DIM);
    }

    #define SCAN_STEP(kc, gc, DO_ST)                                                   \
        do {                                                                           \
            const f16x2 k01 = __builtin_shufflevector((kc), (kc), 0, 1);               \
            const f16x2 k23 = __builtin_shufflevector((kc), (kc), 2, 3);               \
            const f16x2 g01 = __builtin_shufflevector((gc), (gc), 0, 1);               \
            const f16x2 g23 = __builtin_shufflevector((gc), (gc), 2, 3);               \
            const f16x2 u01 = h01 * g01;                                               \
            const f16x2 u23 = h23 * g23;                                               \
            float s = sumsq4(h01, h23);                                                \
            s = dpp_add_f<0xB1>(s);                                                    \
            s = dpp_add_f<0x4E>(s);                                                    \
            s = dpp_add_f<0x141>(s);                                                   \
            s = dpp_add_f<0x140>(s);                                                   \
            const float inv = __builtin_amdgcn_rsqf(fmaf(s, 0.015625f, 1e-8f));        \
            const f16 ih = (f16)inv;                                                   \
            const f16x2 iv = (f16x2){ih, ih};                                          \
            h01 = u01 * iv + k01;                                                      \
            h23 = u23 * iv + k23;                                                      \
            if (DO_ST) {                                                               \
                f16x4 o;                                                               \
                o[0] = h01[0]; o[1] = h01[1]; o[2] = h23[0]; o[3] = h23[1];            \
                *(f16x4*)(Ov + off) = o;                                               \
            }                                                                          \
            off += DIM;                                                                \
        } while (0)

    for (int tb = 0; tb < warm; tb += PF) {
        #pragma unroll
        for (int u = 0; u < PF; ++u) {
            const f16x4 kc = kb[u], gc = gb[u];
            const size_t poff = off + (size_t)PF * DIM;
            kb[u] = *(const f16x4*)(Kv + poff);
            gb[u] = *(const f16x4*)(Gv + poff);
            SCAN_STEP(kc, gc, 0);
        }
    }
    for (int tb = 0; tb < CHK - PF; tb += PF) {
        #pragma unroll
        for (int u = 0; u < PF; ++u) {
            const f16x4 kc = kb[u], gc = gb[u];
            const size_t poff = off + (size_t)PF * DIM;
            kb[u] = *(const f16x4*)(Kv + poff);
            gb[u] = *(const f16x4*)(Gv + poff);
            SCAN_STEP(kc, gc, 1);
        }
    }
    #pragma unroll
    for (int u = 0; u < PF; ++u) {
        const f16x4 kc = kb[u], gc = gb[u];
        SCAN_STEP(kc, gc, 1);
    }
    #undef SCAN_STEP
}

// ---------------------------------------------------------------------------
extern "C" void kernel_launch(void* const* d_in, const int* in_sizes, int n_in,
                              void* d_out, int out_size, void* d_ws, size_t ws_size,
                              hipStream_t stream) {
    const float* x    = (const float*)d_in[0];
    const float* Wk   = (const float*)d_in[1];
    const float* Wkg  = (const float*)d_in[2];
    const float* bkg  = (const float*)d_in[3];
    const float* Wout = (const float*)d_in[4];
    float* out = (float*)d_out;

    // workspace (f16): xh/Kh/Gh 32MB each + Wcat 4MB + Wouth 2MB = 102MB
    f16* xh    = (f16*)d_ws;                         // [M, D]; scan output reuses it
    f16* Kh    = xh    + (size_t)MROWS * DIM;
    f16* Gh    = Kh    + (size_t)MROWS * DIM;
    f16* Wcat  = Gh    + (size_t)MROWS * DIM;        // [2048, 1024]: Wk ; Wkg
    f16* Wouth = Wcat  + (size_t)2 * DIM * DIM;

    // merged converts: one dispatch (x + Wk + Wkg + Wout), 9728 blocks
    cvt_all<<<dim3(9728), dim3(256), 0, stream>>>(x, Wk, Wkg, Wout, xh, Wcat, Wouth);

    // fused k|g GEMM: M=16384, N=2048 -> 64 x 8 = 512 blocks (2/CU resident)
    gemm8<1><<<dim3(512), dim3(512), 0, stream>>>(xh, Wcat, bkg, Kh, Gh);
    // speculative chunked scan: 32 wave-groups x 32 chunks = 1024 blocks
    scan_kernel<<<dim3(1024), dim3(64), 0, stream>>>(Kh, Gh, xh);
    // out = o @ Wout.T: 64 x 4 = 256 blocks
    gemm8<0><<<dim3(256), dim3(512), 0, stream>>>(xh, Wouth, nullptr, out, nullptr);
}